// Round 1
// 199.295 us; speedup vs baseline: 1.0071x; 1.0071x over previous
//
#include <hip/hip_runtime.h>

// Problem constants (from reference)
#define C_IN    7
#define NKER    586
#define KH      8
#define SEQ     4096
#define T_LEN   (SEQ * 3)      // 12288 gathered positions
#define HP      (T_LEN + 1)    // 12289 output positions
#define NC      4096           // output channels (7*585 + 1)
#define KO_N    585            // kernels per g-channel for the main block

#define H_TILE  64
#define BLOCK   256
#define CPT     4              // channels per thread (float4 store)
#define C_PER_BLOCK (BLOCK * CPT)   // 1024
#define GROW    (H_TILE + 7)   // g values needed per channel per tile

__global__ __launch_bounds__(BLOCK) void conv1d_gather_kernel(
    const float* __restrict__ x,      // (SEQ, C_IN)
    const float* __restrict__ kern,   // (NKER, KH, 3)
    float* __restrict__ out)          // flat[h*NC + c]
{
    __shared__ float g[C_IN][GROW + 1];   // +1 pad

    const int h0  = blockIdx.y * H_TILE;
    const int c0  = blockIdx.x * C_PER_BLOCK;
    const int tid = threadIdx.x;

    // ---- Stage g[ci][tt] for t = h0-4 .. h0+H_TILE+2 (zero outside [0,T_LEN)) ----
    const int GCNT = C_IN * GROW;  // 497
    for (int i = tid; i < GCNT; i += BLOCK) {
        int ci = i / GROW;
        int tt = i - ci * GROW;
        int t  = h0 - 4 + tt;
        float v = 0.0f;
        if (t >= 0 && t < T_LEN) {
            int s  = t / 3;
            int j  = t - 3 * s;
            int si = s + j;
            si = (si > SEQ - 1) ? (SEQ - 1) : si;
            v = x[si * C_IN + ci];
        }
        g[ci][tt] = v;
    }
    __syncthreads();

    const int cbase = c0 + tid * CPT;    // multiple of 4, never 4095

    // ---- Per-channel kernel index + g-channel selection (static per thread) ----
    float taps[CPT][KH];
    int   gci[CPT];
    #pragma unroll
    for (int j = 0; j < CPT; j++) {
        int c = cbase + j;
        int gc, kidx;
        if (c == NC - 1) { gc = 0; kidx = NKER - 1; }   // last row: g[0] * kernels[585]
        else             { gc = c / KO_N; kidx = c - KO_N * gc; }
        gci[j] = gc;
        #pragma unroll
        for (int k = 0; k < KH; k++)
            taps[j][k] = kern[kidx * (KH * 3) + k * 3 + 1];   // middle column only
    }

    // ---- One sliding window PER channel, bound to its g row once ----
    // (replaces the dual winA/winB + cndmask scheme: 32 FMA/iter instead of
    //  64 FMA + 4 cndmask; refill is 4 broadcast ds_read_b32)
    float win[CPT][KH];
    #pragma unroll
    for (int j = 0; j < CPT; j++)
        #pragma unroll
        for (int k = 0; k < KH; k++)
            win[j][k] = g[gci[j]][k];

    int hend = HP - h0; if (hend > H_TILE) hend = H_TILE;
    float* outp = out + (size_t)h0 * NC + cbase;

    auto body = [&](int nrows) {
        #pragma unroll 8
        for (int hh = 0; hh < nrows; hh++) {
            float d[CPT];
            #pragma unroll
            for (int j = 0; j < CPT; j++) d[j] = 0.0f;
            #pragma unroll
            for (int k = 0; k < KH; k++) {
                #pragma unroll
                for (int j = 0; j < CPT; j++)
                    d[j] = fmaf(win[j][k], taps[j][k], d[j]);
            }
            float4 o;
            o.x = d[0]; o.y = d[1]; o.z = d[2]; o.w = d[3];
            *reinterpret_cast<float4*>(outp) = o;
            outp += NC;

            // slide each window by one position (register renames under unroll)
            #pragma unroll
            for (int k = 0; k < KH - 1; k++) {
                #pragma unroll
                for (int j = 0; j < CPT; j++)
                    win[j][k] = win[j][k + 1];
            }
            #pragma unroll
            for (int j = 0; j < CPT; j++)
                win[j][KH - 1] = g[gci[j]][hh + KH];
        }
    };

    if (hend == H_TILE) body(H_TILE);   // compile-time trip count for the hot path
    else                body(hend);     // only the last row-tile (hend == 1)
}

extern "C" void kernel_launch(void* const* d_in, const int* in_sizes, int n_in,
                              void* d_out, int out_size, void* d_ws, size_t ws_size,
                              hipStream_t stream) {
    const float* x    = (const float*)d_in[0];   // (1, 4096, 7, 1) f32
    const float* kern = (const float*)d_in[1];   // (586, 8, 3) f32
    float* out        = (float*)d_out;           // 12289*4096 f32

    dim3 grid(NC / C_PER_BLOCK, (HP + H_TILE - 1) / H_TILE);  // (4, 193)
    conv1d_gather_kernel<<<grid, BLOCK, 0, stream>>>(x, kern, out);
}

// Round 2
// 193.357 us; speedup vs baseline: 1.0380x; 1.0307x over previous
//
#include <hip/hip_runtime.h>

// Problem constants (from reference)
#define C_IN    7
#define NKER    586
#define KH      8
#define SEQ     4096
#define T_LEN   (SEQ * 3)      // 12288 gathered positions
#define HP      (T_LEN + 1)    // 12289 output positions
#define NC      4096           // output channels (7*585 + 1)
#define KO_N    585            // kernels per g-channel for the main block

#define H_TILE  64
#define BLOCK   256
#define CPT     4              // channels per thread (float4 store)
#define C_PER_BLOCK (BLOCK * CPT)   // 1024
#define GROW    (H_TILE + 7)   // g values needed per channel per tile

#define TAPS_LD  9                   // padded leading dim (q*9+k) -> 8-way max on readback
#define TAP_CNT  (NKER * KH)         // 4688 staged taps

__global__ __launch_bounds__(BLOCK) void conv1d_gather_kernel(
    const float* __restrict__ x,      // (SEQ, C_IN)
    const float* __restrict__ kern,   // (NKER, KH, 3)
    float* __restrict__ out)          // flat[h*NC + c]
{
    __shared__ float g[C_IN][GROW + 1];          // +1 pad (2 KB)
    __shared__ float tap_lds[NKER * TAPS_LD];    // 586*9 floats = 21.1 KB

    const int h0  = blockIdx.y * H_TILE;
    const int c0  = blockIdx.x * C_PER_BLOCK;
    const int tid = threadIdx.x;

    // ---- Stage ALL middle-column taps coalesced: tap_lds[q*9+k] = kern[q,k,1] ----
    // (replaces per-thread scalar gather: 32 loads/thread x 64 distinct lines/instr
    //  was serializing the per-CU address unit against a poison-cooled L2/L3)
    for (int i = tid; i < TAP_CNT; i += BLOCK) {
        // i = q*8+k  ->  dest q*9+k = i + (i>>3);  src (q*8+k)*3+1 = i*3+1
        tap_lds[i + (i >> 3)] = kern[i * 3 + 1];
    }

    // ---- Stage g[ci][tt] for t = h0-4 .. h0+H_TILE+2 (zero outside [0,T_LEN)) ----
    const int GCNT = C_IN * GROW;  // 497
    for (int i = tid; i < GCNT; i += BLOCK) {
        int ci = i / GROW;
        int tt = i - ci * GROW;
        int t  = h0 - 4 + tt;
        float v = 0.0f;
        if (t >= 0 && t < T_LEN) {
            int s  = t / 3;
            int j  = t - 3 * s;
            int si = s + j;
            si = (si > SEQ - 1) ? (SEQ - 1) : si;
            v = x[si * C_IN + ci];
        }
        g[ci][tt] = v;
    }
    __syncthreads();

    const int cbase = c0 + tid * CPT;    // multiple of 4, never 4095

    // ---- Per-channel kernel index + g-channel selection (static per thread) ----
    float taps[CPT][KH];
    int   gci[CPT];
    #pragma unroll
    for (int j = 0; j < CPT; j++) {
        int c = cbase + j;
        int gc, kidx;
        if (c == NC - 1) { gc = 0; kidx = NKER - 1; }   // last row: g[0] * kernels[585]
        else             { gc = c / KO_N; kidx = c - KO_N * gc; }
        gci[j] = gc;
        #pragma unroll
        for (int k = 0; k < KH; k++)
            taps[j][k] = tap_lds[kidx * TAPS_LD + k];   // LDS readback, 8-way max
    }

    // ---- One sliding window PER channel, bound to its g row once ----
    float win[CPT][KH];
    #pragma unroll
    for (int j = 0; j < CPT; j++)
        #pragma unroll
        for (int k = 0; k < KH; k++)
            win[j][k] = g[gci[j]][k];

    int hend = HP - h0; if (hend > H_TILE) hend = H_TILE;
    float* outp = out + (size_t)h0 * NC + cbase;

    auto body = [&](int nrows) {
        #pragma unroll 8
        for (int hh = 0; hh < nrows; hh++) {
            float d[CPT];
            #pragma unroll
            for (int j = 0; j < CPT; j++) d[j] = 0.0f;
            #pragma unroll
            for (int k = 0; k < KH; k++) {
                #pragma unroll
                for (int j = 0; j < CPT; j++)
                    d[j] = fmaf(win[j][k], taps[j][k], d[j]);
            }
            float4 o;
            o.x = d[0]; o.y = d[1]; o.z = d[2]; o.w = d[3];
            *reinterpret_cast<float4*>(outp) = o;
            outp += NC;

            // slide each window by one position (register renames under unroll)
            #pragma unroll
            for (int k = 0; k < KH - 1; k++) {
                #pragma unroll
                for (int j = 0; j < CPT; j++)
                    win[j][k] = win[j][k + 1];
            }
            #pragma unroll
            for (int j = 0; j < CPT; j++)
                win[j][KH - 1] = g[gci[j]][hh + KH];
        }
    };

    if (hend == H_TILE) body(H_TILE);   // compile-time trip count for the hot path
    else                body(hend);     // only the last row-tile (hend == 1)
}

extern "C" void kernel_launch(void* const* d_in, const int* in_sizes, int n_in,
                              void* d_out, int out_size, void* d_ws, size_t ws_size,
                              hipStream_t stream) {
    const float* x    = (const float*)d_in[0];   // (1, 4096, 7, 1) f32
    const float* kern = (const float*)d_in[1];   // (586, 8, 3) f32
    float* out        = (float*)d_out;           // 12289*4096 f32

    dim3 grid(NC / C_PER_BLOCK, (HP + H_TILE - 1) / H_TILE);  // (4, 193)
    conv1d_gather_kernel<<<grid, BLOCK, 0, stream>>>(x, kern, out);
}